// Round 4
// baseline (195.660 us; speedup 1.0000x reference)
//
#include <hip/hip_runtime.h>
#include <hip/hip_fp16.h>

// PosteriorHiddenTreeMarkovModel — MI355X / gfx950
// R17 = 2-wave-per-subtree node-split + b3/e3 layout revert.
// Post-mortems: R14 (coop mid) null — mid isn't on ordinary waves' critical
// path (stale-flag semantics: phase 3 never waits in steady state).
// R16 (vectorized Bm reads, [g][c] b3/e3) null on loads and REGRESSED writes:
// scalar strided AGENT_ST caused 8x HBM write amplification (1016->7160KB).
// Model: wall == per-wave straight-line path (44 serial node-iterations,
// ~87% stall at 1.75 waves/SIMD; VALUBusy 20% = 26k issue cy / 192k wall).
// Lever: cut serial iterations AND raise TLP. Block = 128 thr = ONE subtree,
// 2 waves cooperate via __syncthreads, 16 node-lanes per level iteration:
// up 18->10 iters, down 18->10. Grid 64 trees x 28 blocks (27 subtree+1 mid).
// LDS 63.4KB -> ~29KB (bW holds 1 subtree) -> ~5 blocks/CU, ~2.5 waves/SIMD.
// Global protocol unchanged: 27 subtrees/tree, same b3/e3 sizes ([c][g]
// layout restored), same trCnt==27 / trFlg flags, same stale-launch
// idempotency. bmG stays [g][m][c] with 2x dwordx4 row loads. Down-e4's
// duplicate bm_row (leaf_beta + Bmv, same xv) merged into one load.
// Launch-0 spin-safety: 1280 resident < 1792 blocks, but tree-contiguous
// mapping => tree 0 fully resident; retirement advances the window; spin
// timeouts remain as backstops.

namespace {

constexpr int kNPT = 3280;
constexpr int kRS  = 72;   // subtree record stride: 64 beta + 8 pre-norm sums
constexpr int kAS  = 68;   // A row stride per (g,p)
constexpr unsigned kMAGIC  = 0x13579BDFu;
constexpr unsigned kMAGIC2 = 0x2468ACEFu;
__device__ __constant__ int LO[6] = {0, 1, 4, 13, 40, 121};
__device__ __constant__ int P3[5] = {1, 3, 9, 27, 81};

#define AGENT_LD(p)    __hip_atomic_load((p), __ATOMIC_RELAXED, __HIP_MEMORY_SCOPE_AGENT)
#define AGENT_ST(p, v) __hip_atomic_store((p), (v), __ATOMIC_RELAXED, __HIP_MEMORY_SCOPE_AGENT)

// Load the 8-float Bm row for (g, xv): pBmg = bmG + g*1024, row at xv*8.
__device__ __forceinline__ void bm_row(const float* __restrict__ pBmg, int xv,
                                       float* m)
{
    const float4 r0 = *(const float4*)(pBmg + (xv << 3));
    const float4 r1 = *(const float4*)(pBmg + (xv << 3) + 4);
    m[0] = r0.x; m[1] = r0.y; m[2] = r0.z; m[3] = r0.w;
    m[4] = r1.x; m[5] = r1.y; m[6] = r1.z; m[7] = r1.w;
}

__device__ __forceinline__ void leaf_beta(const float* __restrict__ sPi,
                                          const float* __restrict__ pBmg,
                                          int p, int xv, int g, float* b)
{
    float m[8];
    bm_row(pBmg, xv, m);
    float s = 0.f;
    #pragma unroll
    for (int c = 0; c < 8; ++c) {
        b[c] = sPi[(c * 3 + p) * 8 + g] * m[c];
        s += b[c];
    }
    float ig = __builtin_amdgcn_rcpf(s);
    #pragma unroll
    for (int c = 0; c < 8; ++c) b[c] *= ig;
}

// acc[i] *= Bm row; returns pre-norm sum
__device__ __forceinline__ float norm_mul(const float* __restrict__ pBmg,
                                          int xv, float* acc)
{
    float m[8];
    bm_row(pBmg, xv, m);
    float s = 0.f;
    #pragma unroll
    for (int i = 0; i < 8; ++i) { acc[i] *= m[i]; s += acc[i]; }
    return s;
}

// acc[i] += (spg*bj[j]) * A[i][j] over j; A row via 2x b128 per j
__device__ __forceinline__ void matvec_acc(const float* __restrict__ arow,
                                           const float* __restrict__ bj,
                                           float spg, float* acc)
{
    #pragma unroll
    for (int j = 0; j < 8; ++j) {
        float4 a0 = *(const float4*)(arow + j * 8);
        float4 a1 = *(const float4*)(arow + j * 8 + 4);
        float cjv = spg * bj[j];
        acc[0] = fmaf(a0.x, cjv, acc[0]); acc[1] = fmaf(a0.y, cjv, acc[1]);
        acc[2] = fmaf(a0.z, cjv, acc[2]); acc[3] = fmaf(a0.w, cjv, acc[3]);
        acc[4] = fmaf(a1.x, cjv, acc[4]); acc[5] = fmaf(a1.y, cjv, acc[5]);
        acc[6] = fmaf(a1.z, cjv, acc[6]); acc[7] = fmaf(a1.w, cjv, acc[7]);
    }
}

__global__ __launch_bounds__(128, 2)
void fused(const float* __restrict__ lamA, const float* __restrict__ lamB,
           const float* __restrict__ lamPi, const float* __restrict__ lamSP,
           const int* __restrict__ x, float* __restrict__ out,
           unsigned* __restrict__ sy, float* __restrict__ bmG,
           float* __restrict__ b3, float* __restrict__ e3)
{
    const int tid = threadIdx.x, w = tid >> 6, lane = tid & 63;
    const int n = lane >> 3, g = lane & 7;
    const int vn = (w << 3) + n;     // 16 node-lanes across the 2 waves
    __shared__ __align__(16) float sAg[24 * kAS];   // A    [g][p][j][i]
    __shared__ __align__(16) float sLAg[24 * kAS];  // AlogA same layout
    __shared__ float sPi[192], sLPi[192], sSP[24], sLSP[24];
    __shared__ float bw[40 * kRS];                  // this subtree's records
    __shared__ __half bMidH[13 * 64];               // mid beta, fp16
    __shared__ float sMs[13 * 8];                   // mid pre-norm sums
    __shared__ unsigned char xw[124];
    unsigned* trCnt = sy + 32;
    unsigned* trFlg = sy + 2080;

    // ---- init gate ----
    if (tid == 0) {
        if (blockIdx.x == 0) {
            for (int i = 0; i < 64; ++i) AGENT_ST(&trCnt[i * 32], 0u);
            __builtin_amdgcn_s_waitcnt(0);
            AGENT_ST(&sy[0], kMAGIC);
        }
        unsigned long sp = 0;
        while (AGENT_LD(&sy[0]) != kMAGIC) {
            if (++sp > (1UL << 24)) break;
            __builtin_amdgcn_s_sleep(2);
        }
    }
    __syncthreads();

    // ================= phase 0: parameters =================
    if (blockIdx.x == 0) {   // Bm softmax -> bmG [g][m][c] + flag
        float* rr = &bw[0];
        for (int pp = tid; pp < 256; pp += 128) {
            int row = pp >> 2, part = pp & 3;
            int c = row >> 3, gg = row & 7, m0 = part * 32;
            float mx = -1e30f;
            for (int mm = 0; mm < 32; ++mm)
                mx = fmaxf(mx, lamB[(c * 128 + m0 + mm) * 8 + gg]);
            rr[pp] = mx;
        }
        __syncthreads();
        for (int pp = tid; pp < 256; pp += 128) {
            int row = pp >> 2, part = pp & 3;
            int c = row >> 3, gg = row & 7, m0 = part * 32;
            float m4 = fmaxf(fmaxf(rr[row * 4], rr[row * 4 + 1]),
                             fmaxf(rr[row * 4 + 2], rr[row * 4 + 3]));
            float s = 0.f;
            for (int mm = 0; mm < 32; ++mm)
                s += expf(lamB[(c * 128 + m0 + mm) * 8 + gg] - m4);
            rr[256 + pp] = s;
        }
        __syncthreads();
        for (int pp = tid; pp < 256; pp += 128) {
            int row = pp >> 2, part = pp & 3;
            int c = row >> 3, gg = row & 7, m0 = part * 32;
            float m4 = fmaxf(fmaxf(rr[row * 4], rr[row * 4 + 1]),
                             fmaxf(rr[row * 4 + 2], rr[row * 4 + 3]));
            float stot = rr[256 + row * 4] + rr[256 + row * 4 + 1]
                       + rr[256 + row * 4 + 2] + rr[256 + row * 4 + 3];
            float inv = 1.f / stot;
            for (int mm = 0; mm < 32; ++mm)
                AGENT_ST(&bmG[(gg * 128 + m0 + mm) * 8 + c],
                         expf(lamB[(c * 128 + m0 + mm) * 8 + gg] - m4) * inv);
        }
        __syncthreads();
        if (tid == 0) AGENT_ST(&sy[4], kMAGIC2);
    }
    for (int col = tid; col < 192; col += 128) {   // A softmax over i -> g-major
        int j = col / 24; int rem = col - j * 24; int p = rem >> 3; int gg = rem & 7;
        float v[8]; float mx = -1e30f;
        #pragma unroll
        for (int i = 0; i < 8; ++i) {
            v[i] = lamA[((i * 8 + j) * 3 + p) * 8 + gg];
            mx = fmaxf(mx, v[i]);
        }
        float s = 0.f;
        #pragma unroll
        for (int i = 0; i < 8; ++i) { v[i] = expf(v[i] - mx); s += v[i]; }
        float inv = 1.f / s;
        int base = (gg * 3 + p) * kAS + j * 8;
        #pragma unroll
        for (int i = 0; i < 8; ++i) {
            float sm = v[i] * inv;
            sAg[base + i]  = sm;
            sLAg[base + i] = sm * logf(sm);
        }
    }
    for (int col = tid; col < 24; col += 128) {    // Pi softmax over c
        int p = col >> 3; int gg = col & 7;
        float v[8]; float mx = -1e30f;
        #pragma unroll
        for (int c = 0; c < 8; ++c) {
            v[c] = lamPi[(c * 3 + p) * 8 + gg];
            mx = fmaxf(mx, v[c]);
        }
        float s = 0.f;
        #pragma unroll
        for (int c = 0; c < 8; ++c) { v[c] = expf(v[c] - mx); s += v[c]; }
        float inv = 1.f / s;
        #pragma unroll
        for (int c = 0; c < 8; ++c) {
            int idx = (c * 3 + p) * 8 + gg;
            float sm = v[c] * inv;
            sPi[idx]  = sm;
            sLPi[idx] = logf(sm);
        }
    }
    if (tid < 8) {                                 // SP softmax over p
        int gg = tid;
        float v0 = lamSP[gg], v1 = lamSP[8 + gg], v2 = lamSP[16 + gg];
        float mx = fmaxf(v0, fmaxf(v1, v2));
        float e0 = expf(v0 - mx), e1 = expf(v1 - mx), e2 = expf(v2 - mx);
        float inv = 1.f / (e0 + e1 + e2);
        sSP[gg] = e0 * inv; sSP[8 + gg] = e1 * inv; sSP[16 + gg] = e2 * inv;
        sLSP[gg] = logf(e0 * inv); sLSP[8 + gg] = logf(e1 * inv); sLSP[16 + gg] = logf(e2 * inv);
    }
    if (tid == 0) {        // Bm gate: one fence per block per launch
        unsigned long sp = 0;
        while (AGENT_LD(&sy[4]) != kMAGIC2) {
            if (++sp > (1UL << 24)) break;
            __builtin_amdgcn_s_sleep(2);
        }
        __threadfence();
    }
    __syncthreads();

    const float* pBmg = bmG + (g << 10);   // per-lane Bm row base [g][m][c]
    // mapping: 28 blocks per tree; rb 0..26 = subtree block, rb 27 = mid block
    const int t = blockIdx.x / 28, rb = blockIdx.x - t * 28;
    const int id = t * 27 + rb;         // valid only for rb < 27
    const int xb = t * kNPT;

    if (rb < 27) {
        // ================= phase 1: subtree up-pass (2 waves coop) =========
        for (int u = tid; u < 121; u += 128) {
            int gx;
            if (u == 0)       gx = 13 + rb;
            else if (u < 4)   gx = 40  + rb * 3  + (u - 1);
            else if (u < 13)  gx = 121 + rb * 9  + (u - 4);
            else if (u < 40)  gx = 364 + rb * 27 + (u - 13);
            else              gx = 1093 + rb * 81 + (u - 40);
            xw[u] = (unsigned char)x[xb + gx];
        }
        __syncthreads();

        for (int e = 3; e >= 0; --e) {
            int cnt = P3[e];
            for (int base = 0; base < cnt; base += 16) {
                int node = base + vn;
                if (node < cnt) {
                    float acc[8];
                    #pragma unroll
                    for (int i = 0; i < 8; ++i) acc[i] = 0.f;
                    #pragma unroll
                    for (int k = 0; k < 3; ++k) {
                        float bj[8];
                        if (e == 3) {
                            leaf_beta(sPi, pBmg, k, xw[40 + 3 * node + k], g, bj);
                        } else {
                            int co = (LO[e + 1] + 3 * node + k) * kRS + g;
                            #pragma unroll
                            for (int j = 0; j < 8; ++j) bj[j] = bw[co + j * 8];
                        }
                        matvec_acc(&sAg[(g * 3 + k) * kAS], bj, sSP[k * 8 + g], acc);
                    }
                    if (e == 0) {
                        #pragma unroll
                        for (int i = 0; i < 8; ++i) bw[i * 8 + g] = acc[i];  // raw tb root
                        float s = norm_mul(pBmg, xw[0], acc);
                        float ig = __builtin_amdgcn_rcpf(s);
                        #pragma unroll
                        for (int i = 0; i < 8; ++i)
                            AGENT_ST(&b3[id * 64 + i * 8 + g], acc[i] * ig);
                    } else {
                        int slot = LO[e] + node;
                        float s = norm_mul(pBmg, xw[slot], acc);
                        float ig = __builtin_amdgcn_rcpf(s);
                        int bo = slot * kRS + g;
                        #pragma unroll
                        for (int i = 0; i < 8; ++i) bw[bo + i * 8] = acc[i] * ig;
                        bw[slot * kRS + 64 + g] = s;
                    }
                }
            }
            __syncthreads();
        }
        __builtin_amdgcn_s_waitcnt(0);
        if (tid == 0)
            __hip_atomic_fetch_add(&trCnt[t * 32], 1u, __ATOMIC_RELAXED,
                                   __HIP_MEMORY_SCOPE_AGENT);

        // ---- wait for mid, then down-pass ----
        {
            unsigned long sp = 0;
            while (AGENT_LD(&trFlg[t * 32]) != kMAGIC2) {
                if (++sp > (1UL << 22)) break;
                __builtin_amdgcn_s_sleep(1);
            }
        }
        if (w == 0)
            bw[lane] = AGENT_LD(&e3[id * 64 + lane]) * __builtin_amdgcn_rcpf(bw[lane]);
        __syncthreads();

        float ell = 0.f;
        for (int e = 1; e <= 4; ++e) {
            int cnt = P3[e], pl0 = LO[e - 1];
            for (int base = 0; base < cnt; base += 16) {
                int ci = base + vn;
                if (ci < cnt) {
                    int p = ci % 3;
                    int ps = (pl0 + ci / 3) * kRS + g;
                    float r[8];
                    #pragma unroll
                    for (int i = 0; i < 8; ++i) r[i] = bw[ps + i * 8];
                    float bj[8]; float sv = 0.f;
                    float Bmv[8];
                    if (e == 4) {
                        int xv = xw[40 + ci];
                        bm_row(pBmg, xv, Bmv);     // one load, used twice
                        float s = 0.f;
                        #pragma unroll
                        for (int c = 0; c < 8; ++c) {
                            bj[c] = sPi[(c * 3 + p) * 8 + g] * Bmv[c];
                            s += bj[c];
                        }
                        float ig = __builtin_amdgcn_rcpf(s);
                        #pragma unroll
                        for (int c = 0; c < 8; ++c) bj[c] *= ig;
                    } else {
                        int slot = LO[e] + ci;
                        bm_row(pBmg, xw[slot], Bmv);
                        int co = slot * kRS + g;
                        #pragma unroll
                        for (int j = 0; j < 8; ++j) bj[j] = bw[co + j * 8];
                        sv = bw[slot * kRS + 64 + g];
                    }
                    float spg = sSP[p * 8 + g];
                    const float* arow = &sAg[(g * 3 + p) * kAS];
                    const float* lrow = &sLAg[(g * 3 + p) * kAS];
                    float esum = 0.f, lg = 0.f;
                    float ev[8];
                    #pragma unroll
                    for (int j = 0; j < 8; ++j) {
                        float4 a0 = *(const float4*)(arow + j * 8);
                        float4 a1 = *(const float4*)(arow + j * 8 + 4);
                        float4 l0 = *(const float4*)(lrow + j * 8);
                        float4 l1 = *(const float4*)(lrow + j * 8 + 4);
                        float s1 = r[0] * a0.x; s1 = fmaf(r[1], a0.y, s1);
                        s1 = fmaf(r[2], a0.z, s1); s1 = fmaf(r[3], a0.w, s1);
                        s1 = fmaf(r[4], a1.x, s1); s1 = fmaf(r[5], a1.y, s1);
                        s1 = fmaf(r[6], a1.z, s1); s1 = fmaf(r[7], a1.w, s1);
                        float s2 = r[0] * l0.x; s2 = fmaf(r[1], l0.y, s2);
                        s2 = fmaf(r[2], l0.z, s2); s2 = fmaf(r[3], l0.w, s2);
                        s2 = fmaf(r[4], l1.x, s2); s2 = fmaf(r[5], l1.y, s2);
                        s2 = fmaf(r[6], l1.z, s2); s2 = fmaf(r[7], l1.w, s2);
                        float bs = spg * bj[j];
                        ev[j] = bs * s1;
                        lg    = fmaf(bs, s2, lg);
                        esum += ev[j];
                    }
                    lg = fmaf(esum, sLSP[p * 8 + g], lg);
                    #pragma unroll
                    for (int c = 0; c < 8; ++c)
                        lg = fmaf(ev[c], Bmv[c], lg);
                    if (e < 4) {
                        int slot = LO[e] + ci;
                        int co = slot * kRS + g;
                        #pragma unroll
                        for (int j = 0; j < 8; ++j)
                            bw[co + j * 8] = ev[j] * Bmv[j]
                                * __builtin_amdgcn_rcpf(bj[j] * sv);
                    } else {
                        #pragma unroll
                        for (int c = 0; c < 8; ++c)
                            lg = fmaf(ev[c], sLPi[(c * 3 + p) * 8 + g], lg);
                    }
                    ell += lg;
                }
            }
            __syncthreads();
        }

        ell += __shfl_xor(ell, 8);
        ell += __shfl_xor(ell, 16);
        ell += __shfl_xor(ell, 32);
        if (n == 0) atomicAdd(&out[t * 8 + g], -ell);
        return;
    }

    // ===== phase 2: mid (levels 0-3), dedicated block rb==27, 2 waves =====
    {
        unsigned long sp = 0;
        while (AGENT_LD(&trCnt[t * 32]) < 27u) {
            if (++sp > (1UL << 22)) break;
            __builtin_amdgcn_s_sleep(1);
        }
    }
    __threadfence();   // one invalidate; b3 then read via cached loads
    __syncthreads();

    float ellm = 0.f;

    for (int f = 2; f >= 0; --f) {     // ---- up: one pass per level ----
        int cnt = (f == 2) ? 9 : (f == 1 ? 3 : 1);
        int pl0 = (f == 2) ? 4 : (f == 1 ? 1 : 0);
        int cl0 = (f == 1) ? 4 : 1;
        int pi = vn;
        if (pi < cnt) {
            float acc[8];
            #pragma unroll
            for (int i = 0; i < 8; ++i) acc[i] = 0.f;
            #pragma unroll
            for (int k = 0; k < 3; ++k) {
                float bj[8];
                if (f == 2) {
                    const float* src = b3 + (t * 27 + 3 * pi + k) * 64 + g;
                    #pragma unroll
                    for (int j = 0; j < 8; ++j) bj[j] = src[j * 8];
                } else {
                    int co = (cl0 + 3 * pi + k) * 64 + g;
                    #pragma unroll
                    for (int j = 0; j < 8; ++j)
                        bj[j] = __half2float(bMidH[co + j * 8]);
                }
                matvec_acc(&sAg[(g * 3 + k) * kAS], bj, sSP[k * 8 + g], acc);
            }
            int slot = pl0 + pi;
            float s = norm_mul(pBmg, x[xb + slot], acc);
            float ig = __builtin_amdgcn_rcpf(s);
            int bo = slot * 64 + g;
            #pragma unroll
            for (int i = 0; i < 8; ++i)
                bMidH[bo + i * 8] = __float2half(acc[i] * ig);
            sMs[slot * 8 + g] = s;
        }
        __syncthreads();
    }
    if (w == 0 && n == 0) {   // root: ell Bm term; slot0 := r = Bm/s
        float m[8];
        bm_row(pBmg, x[xb], m);
        float invs = __builtin_amdgcn_rcpf(sMs[g]);
        #pragma unroll
        for (int c = 0; c < 8; ++c)
            ellm += __half2float(bMidH[c * 8 + g]) * m[c];
        #pragma unroll
        for (int c = 0; c < 8; ++c)
            bMidH[c * 8 + g] = __float2half(m[c] * invs);
    }
    __syncthreads();
    for (int f = 1; f <= 3; ++f) {     // ---- down: one pass per level ----
        int cnt = (f == 1) ? 3 : (f == 2 ? 9 : 27);
        int cl0 = (f == 1) ? 1 : (f == 2 ? 4 : 13);
        int pl0 = (f == 1) ? 0 : (f == 2 ? 1 : 4);
        for (int base = 0; base < cnt; base += 16) {
            int ci = base + vn;
            if (ci < cnt) {
                int p = ci % 3;
                int ps = (pl0 + ci / 3) * 64 + g;
                float r[8];
                #pragma unroll
                for (int i = 0; i < 8; ++i) r[i] = __half2float(bMidH[ps + i * 8]);
                float bj[8]; float sv = 0.f;
                if (f == 3) {
                    const float* src = b3 + (t * 27 + ci) * 64 + g;
                    #pragma unroll
                    for (int j = 0; j < 8; ++j) bj[j] = src[j * 8];
                } else {
                    int co = (cl0 + ci) * 64 + g;
                    #pragma unroll
                    for (int j = 0; j < 8; ++j) bj[j] = __half2float(bMidH[co + j * 8]);
                    sv = sMs[(cl0 + ci) * 8 + g];
                }
                float spg = sSP[p * 8 + g];
                const float* arow = &sAg[(g * 3 + p) * kAS];
                const float* lrow = &sLAg[(g * 3 + p) * kAS];
                float esum = 0.f, lg = 0.f;
                float ev[8];
                #pragma unroll
                for (int j = 0; j < 8; ++j) {
                    float4 a0 = *(const float4*)(arow + j * 8);
                    float4 a1 = *(const float4*)(arow + j * 8 + 4);
                    float4 l0 = *(const float4*)(lrow + j * 8);
                    float4 l1 = *(const float4*)(lrow + j * 8 + 4);
                    float s1 = r[0] * a0.x; s1 = fmaf(r[1], a0.y, s1);
                    s1 = fmaf(r[2], a0.z, s1); s1 = fmaf(r[3], a0.w, s1);
                    s1 = fmaf(r[4], a1.x, s1); s1 = fmaf(r[5], a1.y, s1);
                    s1 = fmaf(r[6], a1.z, s1); s1 = fmaf(r[7], a1.w, s1);
                    float s2 = r[0] * l0.x; s2 = fmaf(r[1], l0.y, s2);
                    s2 = fmaf(r[2], l0.z, s2); s2 = fmaf(r[3], l0.w, s2);
                    s2 = fmaf(r[4], l1.x, s2); s2 = fmaf(r[5], l1.y, s2);
                    s2 = fmaf(r[6], l1.z, s2); s2 = fmaf(r[7], l1.w, s2);
                    float bs = spg * bj[j];
                    ev[j] = bs * s1;
                    lg    = fmaf(bs, s2, lg);
                    esum += ev[j];
                }
                lg = fmaf(esum, sLSP[p * 8 + g], lg);
                float Bmv[8];
                bm_row(pBmg, x[xb + cl0 + ci], Bmv);
                #pragma unroll
                for (int c = 0; c < 8; ++c)
                    lg = fmaf(ev[c], Bmv[c], lg);
                if (f == 3) {
                    #pragma unroll
                    for (int j = 0; j < 8; ++j)
                        AGENT_ST(&e3[(t * 27 + ci) * 64 + j * 8 + g], ev[j]);
                } else {
                    int co = (cl0 + ci) * 64 + g;
                    #pragma unroll
                    for (int j = 0; j < 8; ++j)
                        bMidH[co + j * 8] = __float2half(
                            ev[j] * Bmv[j] * __builtin_amdgcn_rcpf(bj[j] * sv));
                }
                ellm += lg;
            }
        }
        __syncthreads();
    }
    ellm += __shfl_xor(ellm, 8);
    ellm += __shfl_xor(ellm, 16);
    ellm += __shfl_xor(ellm, 32);
    if (n == 0) atomicAdd(&out[t * 8 + g], -ellm);
    __builtin_amdgcn_s_waitcnt(0);
    __syncthreads();
    if (tid == 0) AGENT_ST(&trFlg[t * 32], kMAGIC2);
}

} // namespace

extern "C" void kernel_launch(void* const* d_in, const int* in_sizes, int n_in,
                              void* d_out, int out_size, void* d_ws, size_t ws_size,
                              hipStream_t stream) {
    const float* lamA  = (const float*)d_in[0];
    const float* lamB  = (const float*)d_in[1];
    const float* lamPi = (const float*)d_in[2];
    const float* lamSP = (const float*)d_in[3];
    const int*   x     = (const int*)d_in[4];
    float* out = (float*)d_out;
    unsigned* sy  = (unsigned*)d_ws;        // sync area (32 KB)
    float* bmG = (float*)d_ws + 8192;       // 8192 floats [g][m][c]
    float* b3  = bmG + 8192;                // 1728*64, rows [c][g]
    float* e3  = b3 + 1728 * 64;            // 1728*64, rows [c][g]

    fused<<<dim3(1792), dim3(128), 0, stream>>>(
        lamA, lamB, lamPi, lamSP, x, out, sy, bmG, b3, e3);
}

// Round 5
// 153.919 us; speedup vs baseline: 1.2712x; 1.2712x over previous
//
#include <hip/hip_runtime.h>
#include <hip/hip_fp16.h>

// PosteriorHiddenTreeMarkovModel — MI355X / gfx950
// R18 = R15 structure + 2-node ILP pairing in hot loops + layout fixes.
// Post-mortems: R17 (1792 blocks, 2-wave subtree split) regressed 82.6->137.8
// = 80us x (1792/~1024 resident) — per-block time did NOT shrink => level
// iterations already overlap; the chain is level-to-level only. Occupancy is
// GRID-limited (448 blocks / 256 CU = 1.75/CU): LDS cuts can't raise TLP,
// more blocks trigger dispatch rounds (R17) or redundancy (R10-12).
// Lever left: per-wave ILP. Each hot-loop body processes TWO independent
// nodes in one basic block (no guards between chains) so the compiler
// interleaves two latency chains: down 81 -> 5 pairs + 1, 27 -> 1 pair + 2;
// up leaf level 27 -> 1 pair + 2 with SHARED A-row loads (dual matvec).
// Layouts: b3/e3 back to [c][g] scalar AGENT_ST (R16's [g][c] scalar stores
// caused 8x HBM write amplification, 1016->7160KB); bmG stays [g][m][c]
// (2x dwordx4 per Bm row). Protocol identical to R15: 448 blocks = 64 trees
// x 7, coop 4-wave mid on rb==6, stale-flag idempotent handoff, spin-safe.

namespace {

constexpr int kNPT = 3280;
constexpr int kRS  = 72;   // subtree record stride: 64 beta + 8 pre-norm sums
constexpr int kAS  = 68;   // A row stride per (g,p)
constexpr unsigned kMAGIC  = 0x13579BDFu;
constexpr unsigned kMAGIC2 = 0x2468ACEFu;
__device__ __constant__ int LO[6] = {0, 1, 4, 13, 40, 121};
__device__ __constant__ int P3[5] = {1, 3, 9, 27, 81};

#define AGENT_LD(p)    __hip_atomic_load((p), __ATOMIC_RELAXED, __HIP_MEMORY_SCOPE_AGENT)
#define AGENT_ST(p, v) __hip_atomic_store((p), (v), __ATOMIC_RELAXED, __HIP_MEMORY_SCOPE_AGENT)

// Load the 8-float Bm row for (g, xv): pBmg = bmG + g*1024, row at xv*8.
__device__ __forceinline__ void bm_row(const float* __restrict__ pBmg, int xv,
                                       float* m)
{
    const float4 r0 = *(const float4*)(pBmg + (xv << 3));
    const float4 r1 = *(const float4*)(pBmg + (xv << 3) + 4);
    m[0] = r0.x; m[1] = r0.y; m[2] = r0.z; m[3] = r0.w;
    m[4] = r1.x; m[5] = r1.y; m[6] = r1.z; m[7] = r1.w;
}

__device__ __forceinline__ void leaf_beta(const float* __restrict__ sPi,
                                          const float* __restrict__ pBmg,
                                          int p, int xv, int g, float* b)
{
    float m[8];
    bm_row(pBmg, xv, m);
    float s = 0.f;
    #pragma unroll
    for (int c = 0; c < 8; ++c) {
        b[c] = sPi[(c * 3 + p) * 8 + g] * m[c];
        s += b[c];
    }
    float ig = __builtin_amdgcn_rcpf(s);
    #pragma unroll
    for (int c = 0; c < 8; ++c) b[c] *= ig;
}

// acc[i] *= Bm row; returns pre-norm sum
__device__ __forceinline__ float norm_mul(const float* __restrict__ pBmg,
                                          int xv, float* acc)
{
    float m[8];
    bm_row(pBmg, xv, m);
    float s = 0.f;
    #pragma unroll
    for (int i = 0; i < 8; ++i) { acc[i] *= m[i]; s += acc[i]; }
    return s;
}

// acc[i] += (spg*bj[j]) * A[i][j] over j; A row via 2x b128 per j
__device__ __forceinline__ void matvec_acc(const float* __restrict__ arow,
                                           const float* __restrict__ bj,
                                           float spg, float* acc)
{
    #pragma unroll
    for (int j = 0; j < 8; ++j) {
        float4 a0 = *(const float4*)(arow + j * 8);
        float4 a1 = *(const float4*)(arow + j * 8 + 4);
        float cjv = spg * bj[j];
        acc[0] = fmaf(a0.x, cjv, acc[0]); acc[1] = fmaf(a0.y, cjv, acc[1]);
        acc[2] = fmaf(a0.z, cjv, acc[2]); acc[3] = fmaf(a0.w, cjv, acc[3]);
        acc[4] = fmaf(a1.x, cjv, acc[4]); acc[5] = fmaf(a1.y, cjv, acc[5]);
        acc[6] = fmaf(a1.z, cjv, acc[6]); acc[7] = fmaf(a1.w, cjv, acc[7]);
    }
}

// dual matvec: shared A-row loads, two independent accumulator chains
__device__ __forceinline__ void matvec2_acc(const float* __restrict__ arow,
                                            const float* bj0, const float* bj1,
                                            float sc0, float sc1,
                                            float* acc0, float* acc1)
{
    #pragma unroll
    for (int j = 0; j < 8; ++j) {
        float4 a0 = *(const float4*)(arow + j * 8);
        float4 a1 = *(const float4*)(arow + j * 8 + 4);
        float c0 = sc0 * bj0[j], c1 = sc1 * bj1[j];
        acc0[0] = fmaf(a0.x, c0, acc0[0]); acc0[1] = fmaf(a0.y, c0, acc0[1]);
        acc0[2] = fmaf(a0.z, c0, acc0[2]); acc0[3] = fmaf(a0.w, c0, acc0[3]);
        acc0[4] = fmaf(a1.x, c0, acc0[4]); acc0[5] = fmaf(a1.y, c0, acc0[5]);
        acc0[6] = fmaf(a1.z, c0, acc0[6]); acc0[7] = fmaf(a1.w, c0, acc0[7]);
        acc1[0] = fmaf(a0.x, c1, acc1[0]); acc1[1] = fmaf(a0.y, c1, acc1[1]);
        acc1[2] = fmaf(a0.z, c1, acc1[2]); acc1[3] = fmaf(a0.w, c1, acc1[3]);
        acc1[4] = fmaf(a1.x, c1, acc1[4]); acc1[5] = fmaf(a1.y, c1, acc1[5]);
        acc1[6] = fmaf(a1.z, c1, acc1[6]); acc1[7] = fmaf(a1.w, c1, acc1[7]);
    }
}

// down-pass inner: ev[j] = spg*bj[j]*dot(r,A_j); lg += spg*bj[j]*dot(r,AlogA_j)
__device__ __forceinline__ void dn_body(const float* r, const float* bj, float spg,
                                        const float* __restrict__ arow,
                                        const float* __restrict__ lrow,
                                        float* ev, float& esum, float& lg)
{
    #pragma unroll
    for (int j = 0; j < 8; ++j) {
        float4 a0 = *(const float4*)(arow + j * 8);
        float4 a1 = *(const float4*)(arow + j * 8 + 4);
        float4 l0 = *(const float4*)(lrow + j * 8);
        float4 l1 = *(const float4*)(lrow + j * 8 + 4);
        float s1 = r[0] * a0.x; s1 = fmaf(r[1], a0.y, s1);
        s1 = fmaf(r[2], a0.z, s1); s1 = fmaf(r[3], a0.w, s1);
        s1 = fmaf(r[4], a1.x, s1); s1 = fmaf(r[5], a1.y, s1);
        s1 = fmaf(r[6], a1.z, s1); s1 = fmaf(r[7], a1.w, s1);
        float s2 = r[0] * l0.x; s2 = fmaf(r[1], l0.y, s2);
        s2 = fmaf(r[2], l0.z, s2); s2 = fmaf(r[3], l0.w, s2);
        s2 = fmaf(r[4], l1.x, s2); s2 = fmaf(r[5], l1.y, s2);
        s2 = fmaf(r[6], l1.z, s2); s2 = fmaf(r[7], l1.w, s2);
        float bs = spg * bj[j];
        ev[j] = bs * s1;
        lg    = fmaf(bs, s2, lg);
        esum += ev[j];
    }
}

__global__ __launch_bounds__(256, 2)
void fused(const float* __restrict__ lamA, const float* __restrict__ lamB,
           const float* __restrict__ lamPi, const float* __restrict__ lamSP,
           const int* __restrict__ x, float* __restrict__ out,
           unsigned* __restrict__ sy, float* __restrict__ bmG,
           float* __restrict__ b3, float* __restrict__ e3)
{
    const int tid = threadIdx.x, w = tid >> 6, lane = tid & 63;
    const int n = lane >> 3, g = lane & 7;
    __shared__ __align__(16) float sAg[24 * kAS];   // A    [g][p][j][i]
    __shared__ __align__(16) float sLAg[24 * kAS];  // AlogA same layout
    __shared__ float sPi[192], sLPi[192], sSP[24], sLSP[24];
    __shared__ float bW[4][40 * kRS];               // per-subtree records
    __shared__ __half bMidH[13 * 64];               // mid beta, fp16
    __shared__ float sMs[13 * 8];                   // mid pre-norm sums
    __shared__ unsigned char xW[4][124];
    unsigned* trCnt = sy + 32;
    unsigned* trFlg = sy + 2080;

    // ---- init gate ----
    if (tid == 0) {
        if (blockIdx.x == 0) {
            for (int i = 0; i < 64; ++i) AGENT_ST(&trCnt[i * 32], 0u);
            __builtin_amdgcn_s_waitcnt(0);
            AGENT_ST(&sy[0], kMAGIC);
        }
        unsigned long sp = 0;
        while (AGENT_LD(&sy[0]) != kMAGIC) {
            if (++sp > (1UL << 24)) break;
            __builtin_amdgcn_s_sleep(2);
        }
    }
    __syncthreads();

    // ================= phase 0: parameters =================
    if (blockIdx.x == 0) {   // Bm softmax -> bmG [g][m][c] + flag
        float* rr = &bW[0][0];
        int row = tid >> 2, part = tid & 3;
        int c = row >> 3, gg = row & 7, m0 = part * 32;
        float mx = -1e30f;
        for (int mm = 0; mm < 32; ++mm)
            mx = fmaxf(mx, lamB[(c * 128 + m0 + mm) * 8 + gg]);
        rr[tid] = mx;
        __syncthreads();
        float m4 = fmaxf(fmaxf(rr[row * 4], rr[row * 4 + 1]),
                         fmaxf(rr[row * 4 + 2], rr[row * 4 + 3]));
        float s = 0.f;
        for (int mm = 0; mm < 32; ++mm)
            s += expf(lamB[(c * 128 + m0 + mm) * 8 + gg] - m4);
        rr[256 + tid] = s;
        __syncthreads();
        float stot = rr[256 + row * 4] + rr[256 + row * 4 + 1]
                   + rr[256 + row * 4 + 2] + rr[256 + row * 4 + 3];
        float inv = 1.f / stot;
        for (int mm = 0; mm < 32; ++mm)
            AGENT_ST(&bmG[(gg * 128 + m0 + mm) * 8 + c],
                     expf(lamB[(c * 128 + m0 + mm) * 8 + gg] - m4) * inv);
        __syncthreads();
        if (tid == 0) AGENT_ST(&sy[4], kMAGIC2);
    }
    for (int col = tid; col < 192; col += 256) {   // A softmax over i -> g-major
        int j = col / 24; int rem = col - j * 24; int p = rem >> 3; int gg = rem & 7;
        float v[8]; float mx = -1e30f;
        #pragma unroll
        for (int i = 0; i < 8; ++i) {
            v[i] = lamA[((i * 8 + j) * 3 + p) * 8 + gg];
            mx = fmaxf(mx, v[i]);
        }
        float s = 0.f;
        #pragma unroll
        for (int i = 0; i < 8; ++i) { v[i] = expf(v[i] - mx); s += v[i]; }
        float inv = 1.f / s;
        int base = (gg * 3 + p) * kAS + j * 8;
        #pragma unroll
        for (int i = 0; i < 8; ++i) {
            float sm = v[i] * inv;
            sAg[base + i]  = sm;
            sLAg[base + i] = sm * logf(sm);
        }
    }
    for (int col = tid; col < 24; col += 256) {    // Pi softmax over c
        int p = col >> 3; int gg = col & 7;
        float v[8]; float mx = -1e30f;
        #pragma unroll
        for (int c = 0; c < 8; ++c) {
            v[c] = lamPi[(c * 3 + p) * 8 + gg];
            mx = fmaxf(mx, v[c]);
        }
        float s = 0.f;
        #pragma unroll
        for (int c = 0; c < 8; ++c) { v[c] = expf(v[c] - mx); s += v[c]; }
        float inv = 1.f / s;
        #pragma unroll
        for (int c = 0; c < 8; ++c) {
            int idx = (c * 3 + p) * 8 + gg;
            float sm = v[c] * inv;
            sPi[idx]  = sm;
            sLPi[idx] = logf(sm);
        }
    }
    if (tid < 8) {                                 // SP softmax over p
        int gg = tid;
        float v0 = lamSP[gg], v1 = lamSP[8 + gg], v2 = lamSP[16 + gg];
        float mx = fmaxf(v0, fmaxf(v1, v2));
        float e0 = expf(v0 - mx), e1 = expf(v1 - mx), e2 = expf(v2 - mx);
        float inv = 1.f / (e0 + e1 + e2);
        sSP[gg] = e0 * inv; sSP[8 + gg] = e1 * inv; sSP[16 + gg] = e2 * inv;
        sLSP[gg] = logf(e0 * inv); sLSP[8 + gg] = logf(e1 * inv); sLSP[16 + gg] = logf(e2 * inv);
    }
    if (tid == 0) {        // Bm gate: one fence per block per launch
        unsigned long sp = 0;
        while (AGENT_LD(&sy[4]) != kMAGIC2) {
            if (++sp > (1UL << 24)) break;
            __builtin_amdgcn_s_sleep(2);
        }
        __threadfence();
    }
    __syncthreads();

    const float* pBmg = bmG + (g << 10);   // per-lane Bm row base [g][m][c]
    // tree-aligned mapping: 7 blocks (28 wave slots) per tree.
    // q = 0..26: subtree wave; q == 27 (block rb==6, w==3): mid-only wave.
    const int t = blockIdx.x / 7, rb = blockIdx.x - t * 7;
    const int q = rb * 4 + w;
    const int id = t * 27 + q;          // valid only for q < 27
    const int xb = t * kNPT;
    float* bw = &bW[w][0];
    unsigned char* xw = &xW[w][0];
    float ell = 0.f;

    // ---------------- hot-loop bodies (captured context) ----------------
    auto up1 = [&](int e, int node) {
        float acc[8];
        #pragma unroll
        for (int i = 0; i < 8; ++i) acc[i] = 0.f;
        #pragma unroll
        for (int k = 0; k < 3; ++k) {
            float bj[8];
            if (e == 3) {
                leaf_beta(sPi, pBmg, k, xw[40 + 3 * node + k], g, bj);
            } else {
                int co = (LO[e + 1] + 3 * node + k) * kRS + g;
                #pragma unroll
                for (int j = 0; j < 8; ++j) bj[j] = bw[co + j * 8];
            }
            matvec_acc(&sAg[(g * 3 + k) * kAS], bj, sSP[k * 8 + g], acc);
        }
        if (e == 0) {
            #pragma unroll
            for (int i = 0; i < 8; ++i) bw[i * 8 + g] = acc[i];  // raw tb root
            float s = norm_mul(pBmg, xw[0], acc);
            float ig = __builtin_amdgcn_rcpf(s);
            #pragma unroll
            for (int i = 0; i < 8; ++i)
                AGENT_ST(&b3[id * 64 + i * 8 + g], acc[i] * ig);
        } else {
            int slot = LO[e] + node;
            float s = norm_mul(pBmg, xw[slot], acc);
            float ig = __builtin_amdgcn_rcpf(s);
            int bo = slot * kRS + g;
            #pragma unroll
            for (int i = 0; i < 8; ++i) bw[bo + i * 8] = acc[i] * ig;
            bw[slot * kRS + 64 + g] = s;
        }
    };

    // leaf-level pair (e==3): two nodes, shared A rows, one basic block
    auto up2_leaf = [&](int n0, int n1) {
        float acc0[8], acc1[8];
        #pragma unroll
        for (int i = 0; i < 8; ++i) { acc0[i] = 0.f; acc1[i] = 0.f; }
        #pragma unroll
        for (int k = 0; k < 3; ++k) {
            float m0[8], m1[8];
            bm_row(pBmg, xw[40 + 3 * n0 + k], m0);
            bm_row(pBmg, xw[40 + 3 * n1 + k], m1);
            float b0[8], b1[8]; float s0 = 0.f, s1 = 0.f;
            #pragma unroll
            for (int c = 0; c < 8; ++c) {
                float pi = sPi[(c * 3 + k) * 8 + g];
                b0[c] = pi * m0[c]; s0 += b0[c];
                b1[c] = pi * m1[c]; s1 += b1[c];
            }
            float spg = sSP[k * 8 + g];
            float sc0 = spg * __builtin_amdgcn_rcpf(s0);
            float sc1 = spg * __builtin_amdgcn_rcpf(s1);
            matvec2_acc(&sAg[(g * 3 + k) * kAS], b0, b1, sc0, sc1, acc0, acc1);
        }
        int sl0 = 13 + n0, sl1 = 13 + n1;
        float s0 = norm_mul(pBmg, xw[sl0], acc0);
        float s1 = norm_mul(pBmg, xw[sl1], acc1);
        float ig0 = __builtin_amdgcn_rcpf(s0), ig1 = __builtin_amdgcn_rcpf(s1);
        int bo0 = sl0 * kRS + g, bo1 = sl1 * kRS + g;
        #pragma unroll
        for (int i = 0; i < 8; ++i) {
            bw[bo0 + i * 8] = acc0[i] * ig0;
            bw[bo1 + i * 8] = acc1[i] * ig1;
        }
        bw[sl0 * kRS + 64 + g] = s0;
        bw[sl1 * kRS + 64 + g] = s1;
    };

    auto dn1 = [&](int e, int ci) {
        int p = ci % 3;
        int ps = (LO[e - 1] + ci / 3) * kRS + g;
        float r[8];
        #pragma unroll
        for (int i = 0; i < 8; ++i) r[i] = bw[ps + i * 8];
        float bj[8], Bmv[8]; float sv = 0.f;
        if (e == 4) {
            bm_row(pBmg, xw[40 + ci], Bmv);
            float s = 0.f;
            #pragma unroll
            for (int c = 0; c < 8; ++c) { bj[c] = sPi[(c * 3 + p) * 8 + g] * Bmv[c]; s += bj[c]; }
            float ig = __builtin_amdgcn_rcpf(s);
            #pragma unroll
            for (int c = 0; c < 8; ++c) bj[c] *= ig;
        } else {
            int slot = LO[e] + ci;
            bm_row(pBmg, xw[slot], Bmv);
            int co = slot * kRS + g;
            #pragma unroll
            for (int j = 0; j < 8; ++j) bj[j] = bw[co + j * 8];
            sv = bw[slot * kRS + 64 + g];
        }
        float ev[8]; float esum = 0.f, lg = 0.f;
        dn_body(r, bj, sSP[p * 8 + g],
                &sAg[(g * 3 + p) * kAS], &sLAg[(g * 3 + p) * kAS], ev, esum, lg);
        lg = fmaf(esum, sLSP[p * 8 + g], lg);
        #pragma unroll
        for (int c = 0; c < 8; ++c) lg = fmaf(ev[c], Bmv[c], lg);
        if (e < 4) {
            int slot = LO[e] + ci;
            int co = slot * kRS + g;
            #pragma unroll
            for (int j = 0; j < 8; ++j)
                bw[co + j * 8] = ev[j] * Bmv[j] * __builtin_amdgcn_rcpf(bj[j] * sv);
        } else {
            #pragma unroll
            for (int c = 0; c < 8; ++c) lg = fmaf(ev[c], sLPi[(c * 3 + p) * 8 + g], lg);
        }
        ell += lg;
    };

    // leaf-level down pair (e==4), one basic block, two independent chains
    auto dn2_leaf = [&](int c0, int c1) {
        int p0 = c0 % 3, p1 = c1 % 3;
        int ps0 = (13 + c0 / 3) * kRS + g, ps1 = (13 + c1 / 3) * kRS + g;
        float r0[8], r1[8];
        #pragma unroll
        for (int i = 0; i < 8; ++i) { r0[i] = bw[ps0 + i * 8]; r1[i] = bw[ps1 + i * 8]; }
        float Bmv0[8], Bmv1[8];
        bm_row(pBmg, xw[40 + c0], Bmv0);
        bm_row(pBmg, xw[40 + c1], Bmv1);
        float bj0[8], bj1[8]; float s0 = 0.f, s1 = 0.f;
        #pragma unroll
        for (int c = 0; c < 8; ++c) {
            bj0[c] = sPi[(c * 3 + p0) * 8 + g] * Bmv0[c]; s0 += bj0[c];
            bj1[c] = sPi[(c * 3 + p1) * 8 + g] * Bmv1[c]; s1 += bj1[c];
        }
        float ig0 = __builtin_amdgcn_rcpf(s0), ig1 = __builtin_amdgcn_rcpf(s1);
        #pragma unroll
        for (int c = 0; c < 8; ++c) { bj0[c] *= ig0; bj1[c] *= ig1; }
        float ev0[8], ev1[8];
        float es0 = 0.f, lg0 = 0.f, es1 = 0.f, lg1 = 0.f;
        dn_body(r0, bj0, sSP[p0 * 8 + g],
                &sAg[(g * 3 + p0) * kAS], &sLAg[(g * 3 + p0) * kAS], ev0, es0, lg0);
        dn_body(r1, bj1, sSP[p1 * 8 + g],
                &sAg[(g * 3 + p1) * kAS], &sLAg[(g * 3 + p1) * kAS], ev1, es1, lg1);
        lg0 = fmaf(es0, sLSP[p0 * 8 + g], lg0);
        lg1 = fmaf(es1, sLSP[p1 * 8 + g], lg1);
        #pragma unroll
        for (int c = 0; c < 8; ++c) {
            lg0 = fmaf(ev0[c], Bmv0[c], lg0);
            lg0 = fmaf(ev0[c], sLPi[(c * 3 + p0) * 8 + g], lg0);
            lg1 = fmaf(ev1[c], Bmv1[c], lg1);
            lg1 = fmaf(ev1[c], sLPi[(c * 3 + p1) * 8 + g], lg1);
        }
        ell += lg0 + lg1;
    };

    // interior down pair (e==3): bj from bw, beta update stored back
    auto dn2_store = [&](int c0, int c1) {
        int p0 = c0 % 3, p1 = c1 % 3;
        int ps0 = (4 + c0 / 3) * kRS + g, ps1 = (4 + c1 / 3) * kRS + g;
        float r0[8], r1[8];
        #pragma unroll
        for (int i = 0; i < 8; ++i) { r0[i] = bw[ps0 + i * 8]; r1[i] = bw[ps1 + i * 8]; }
        int sl0 = 13 + c0, sl1 = 13 + c1;
        float Bmv0[8], Bmv1[8];
        bm_row(pBmg, xw[sl0], Bmv0);
        bm_row(pBmg, xw[sl1], Bmv1);
        int co0 = sl0 * kRS + g, co1 = sl1 * kRS + g;
        float bj0[8], bj1[8];
        #pragma unroll
        for (int j = 0; j < 8; ++j) { bj0[j] = bw[co0 + j * 8]; bj1[j] = bw[co1 + j * 8]; }
        float sv0 = bw[sl0 * kRS + 64 + g], sv1 = bw[sl1 * kRS + 64 + g];
        float ev0[8], ev1[8];
        float es0 = 0.f, lg0 = 0.f, es1 = 0.f, lg1 = 0.f;
        dn_body(r0, bj0, sSP[p0 * 8 + g],
                &sAg[(g * 3 + p0) * kAS], &sLAg[(g * 3 + p0) * kAS], ev0, es0, lg0);
        dn_body(r1, bj1, sSP[p1 * 8 + g],
                &sAg[(g * 3 + p1) * kAS], &sLAg[(g * 3 + p1) * kAS], ev1, es1, lg1);
        lg0 = fmaf(es0, sLSP[p0 * 8 + g], lg0);
        lg1 = fmaf(es1, sLSP[p1 * 8 + g], lg1);
        #pragma unroll
        for (int c = 0; c < 8; ++c) {
            lg0 = fmaf(ev0[c], Bmv0[c], lg0);
            lg1 = fmaf(ev1[c], Bmv1[c], lg1);
        }
        #pragma unroll
        for (int j = 0; j < 8; ++j) {
            bw[co0 + j * 8] = ev0[j] * Bmv0[j] * __builtin_amdgcn_rcpf(bj0[j] * sv0);
            bw[co1 + j * 8] = ev1[j] * Bmv1[j] * __builtin_amdgcn_rcpf(bj1[j] * sv1);
        }
        ell += lg0 + lg1;
    };

    // ================= phase 1: subtree up-pass =================
    if (q < 27) {
        for (int u = lane; u < 121; u += 64) {
            int gx;
            if (u == 0)       gx = 13 + q;
            else if (u < 4)   gx = 40  + q * 3  + (u - 1);
            else if (u < 13)  gx = 121 + q * 9  + (u - 4);
            else if (u < 40)  gx = 364 + q * 27 + (u - 13);
            else              gx = 1093 + q * 81 + (u - 40);
            xw[u] = (unsigned char)x[xb + gx];
        }
        __builtin_amdgcn_wave_barrier();

        for (int e = 3; e >= 0; --e) {
            int cnt = P3[e];
            int base = 0;
            if (e == 3) {
                for (; base + 16 <= cnt; base += 16)
                    up2_leaf(base + n, base + 8 + n);
            }
            for (; base < cnt; base += 8) {
                int node = base + n;
                if (node < cnt) up1(e, node);
            }
            __builtin_amdgcn_wave_barrier();
        }
        __builtin_amdgcn_s_waitcnt(0);
        if (lane == 0)
            __hip_atomic_fetch_add(&trCnt[t * 32], 1u, __ATOMIC_RELAXED,
                                   __HIP_MEMORY_SCOPE_AGENT);
    }

    // ===== phase 2: mid (levels 0-3), cooperative 4-wave on block rb==6 =====
    if (rb == 6) {
        {
            unsigned long sp = 0;
            while (AGENT_LD(&trCnt[t * 32]) < 27u) {
                if (++sp > (1UL << 22)) break;
                __builtin_amdgcn_s_sleep(1);
            }
        }
        __threadfence();   // one invalidate; b3 then read via cached loads
        __syncthreads();

        float ellm = 0.f;
        const int vn = (w << 3) + n;       // 32 node-lanes across the block

        for (int f = 2; f >= 0; --f) {     // ---- up: one pass per level ----
            int cnt = (f == 2) ? 9 : (f == 1 ? 3 : 1);
            int pl0 = (f == 2) ? 4 : (f == 1 ? 1 : 0);
            int cl0 = (f == 1) ? 4 : 1;
            int pi = vn;
            if (pi < cnt) {
                float acc[8];
                #pragma unroll
                for (int i = 0; i < 8; ++i) acc[i] = 0.f;
                #pragma unroll
                for (int k = 0; k < 3; ++k) {
                    float bj[8];
                    if (f == 2) {
                        const float* src = b3 + (t * 27 + 3 * pi + k) * 64 + g;
                        #pragma unroll
                        for (int j = 0; j < 8; ++j) bj[j] = src[j * 8];
                    } else {
                        int co = (cl0 + 3 * pi + k) * 64 + g;
                        #pragma unroll
                        for (int j = 0; j < 8; ++j)
                            bj[j] = __half2float(bMidH[co + j * 8]);
                    }
                    matvec_acc(&sAg[(g * 3 + k) * kAS], bj, sSP[k * 8 + g], acc);
                }
                int slot = pl0 + pi;
                float s = norm_mul(pBmg, x[xb + slot], acc);
                float ig = __builtin_amdgcn_rcpf(s);
                int bo = slot * 64 + g;
                #pragma unroll
                for (int i = 0; i < 8; ++i)
                    bMidH[bo + i * 8] = __float2half(acc[i] * ig);
                sMs[slot * 8 + g] = s;
            }
            __syncthreads();
        }
        if (w == 0 && n == 0) {   // root: ell Bm term; slot0 := r = Bm/s
            float m[8];
            bm_row(pBmg, x[xb], m);
            float invs = __builtin_amdgcn_rcpf(sMs[g]);
            #pragma unroll
            for (int c = 0; c < 8; ++c)
                ellm += __half2float(bMidH[c * 8 + g]) * m[c];
            #pragma unroll
            for (int c = 0; c < 8; ++c)
                bMidH[c * 8 + g] = __float2half(m[c] * invs);
        }
        __syncthreads();
        for (int f = 1; f <= 3; ++f) {     // ---- down: one pass per level ----
            int cnt = (f == 1) ? 3 : (f == 2 ? 9 : 27);
            int cl0 = (f == 1) ? 1 : (f == 2 ? 4 : 13);
            int pl0 = (f == 1) ? 0 : (f == 2 ? 1 : 4);
            int ci = vn;
            if (ci < cnt) {
                int p = ci % 3;
                int ps = (pl0 + ci / 3) * 64 + g;
                float r[8];
                #pragma unroll
                for (int i = 0; i < 8; ++i) r[i] = __half2float(bMidH[ps + i * 8]);
                float bj[8]; float sv = 0.f;
                if (f == 3) {
                    const float* src = b3 + (t * 27 + ci) * 64 + g;
                    #pragma unroll
                    for (int j = 0; j < 8; ++j) bj[j] = src[j * 8];
                } else {
                    int co = (cl0 + ci) * 64 + g;
                    #pragma unroll
                    for (int j = 0; j < 8; ++j) bj[j] = __half2float(bMidH[co + j * 8]);
                    sv = sMs[(cl0 + ci) * 8 + g];
                }
                float Bmv[8];
                bm_row(pBmg, x[xb + cl0 + ci], Bmv);
                float ev[8]; float esum = 0.f, lg = 0.f;
                dn_body(r, bj, sSP[p * 8 + g],
                        &sAg[(g * 3 + p) * kAS], &sLAg[(g * 3 + p) * kAS], ev, esum, lg);
                lg = fmaf(esum, sLSP[p * 8 + g], lg);
                #pragma unroll
                for (int c = 0; c < 8; ++c)
                    lg = fmaf(ev[c], Bmv[c], lg);
                if (f == 3) {
                    #pragma unroll
                    for (int j = 0; j < 8; ++j)
                        AGENT_ST(&e3[(t * 27 + ci) * 64 + j * 8 + g], ev[j]);
                } else {
                    int co = (cl0 + ci) * 64 + g;
                    #pragma unroll
                    for (int j = 0; j < 8; ++j)
                        bMidH[co + j * 8] = __float2half(
                            ev[j] * Bmv[j] * __builtin_amdgcn_rcpf(bj[j] * sv));
                }
                ellm += lg;
            }
            __syncthreads();
        }
        ellm += __shfl_xor(ellm, 8);
        ellm += __shfl_xor(ellm, 16);
        ellm += __shfl_xor(ellm, 32);
        if (n == 0) atomicAdd(&out[t * 8 + g], -ellm);
        __builtin_amdgcn_s_waitcnt(0);
        __syncthreads();
        if (tid == 0) AGENT_ST(&trFlg[t * 32], kMAGIC2);
        if (q == 27) return;   // mid-only wave: no subtree, no phase 3
    } else {
        unsigned long sp = 0;
        while (AGENT_LD(&trFlg[t * 32]) != kMAGIC2) {
            if (++sp > (1UL << 22)) break;
            __builtin_amdgcn_s_sleep(1);
        }
    }

    // ================= phase 3: subtree down-pass =================
    bw[lane] = AGENT_LD(&e3[id * 64 + lane]) * __builtin_amdgcn_rcpf(bw[lane]);
    __builtin_amdgcn_wave_barrier();

    for (int e = 1; e <= 4; ++e) {
        int cnt = P3[e];
        int base = 0;
        if (e == 4) {
            for (; base + 16 <= cnt; base += 16)
                dn2_leaf(base + n, base + 8 + n);
        } else if (e == 3) {
            for (; base + 16 <= cnt; base += 16)
                dn2_store(base + n, base + 8 + n);
        }
        for (; base < cnt; base += 8) {
            int ci = base + n;
            if (ci < cnt) dn1(e, ci);
        }
        __builtin_amdgcn_wave_barrier();
    }

    ell += __shfl_xor(ell, 8);
    ell += __shfl_xor(ell, 16);
    ell += __shfl_xor(ell, 32);
    if (n == 0) atomicAdd(&out[t * 8 + g], -ell);
}

} // namespace

extern "C" void kernel_launch(void* const* d_in, const int* in_sizes, int n_in,
                              void* d_out, int out_size, void* d_ws, size_t ws_size,
                              hipStream_t stream) {
    const float* lamA  = (const float*)d_in[0];
    const float* lamB  = (const float*)d_in[1];
    const float* lamPi = (const float*)d_in[2];
    const float* lamSP = (const float*)d_in[3];
    const int*   x     = (const int*)d_in[4];
    float* out = (float*)d_out;
    unsigned* sy  = (unsigned*)d_ws;        // sync area (32 KB)
    float* bmG = (float*)d_ws + 8192;       // 8192 floats [g][m][c]
    float* b3  = bmG + 8192;                // 1728*64, rows [c][g]
    float* e3  = b3 + 1728 * 64;            // 1728*64, rows [c][g]

    fused<<<dim3(448), dim3(256), 0, stream>>>(
        lamA, lamB, lamPi, lamSP, x, out, sy, bmG, b3, e3);
}